// Round 2
// baseline (8537.836 us; speedup 1.0000x reference)
//
#include <hip/hip_runtime.h>
#include <math.h>

// Multislice gradient step. 1024-pt complex fp32 FFT as 3 register-radix-8
// phases (fused radix-2 stages 0-2 / 3-5 / 6-9) with ping-pong LDS exchanges.
// R2: the entire 72-dispatch FFT chain is ONE persistent kernel (k_chain,
// 512 blocks x 256 thr, 2 blocks/CU guaranteed by __launch_bounds__(256,2),
// LDS allows 4/CU -> 2x co-residency slack) with a sense-reversing software
// grid barrier. Twiddles filled once. k_kern uses fp64 frac + fp32 sincosf.
// k_T / k_merge process 64 B/thread.

#define NN (1024*1024)
#define KAPPA 40.840704496667314f
#define TWO_PI_F 6.2831853071795865f
#define DFX_D 0.0030048076923076925
#define RRCUT 187177
#define F(i) ((i) + ((i)>>4))
#define NB 512u

#define JT 0
#define JT_WP 1
#define JN 2
#define JRESID 3

__device__ __forceinline__ float2 cmulf(float2 a, float2 b){
    return make_float2(a.x*b.x - a.y*b.y, a.x*b.y + a.y*b.x);
}
__device__ __forceinline__ float2 cmulcj(float2 a, float2 b){ // a * conj(b)
    return make_float2(a.x*b.x + a.y*b.y, a.y*b.x - a.x*b.y);
}
__device__ __forceinline__ float2 f2add(float2 a, float2 b){ return make_float2(a.x+b.x, a.y+b.y); }
__device__ __forceinline__ float2 f2sub(float2 a, float2 b){ return make_float2(a.x-b.x, a.y-b.y); }

__device__ __forceinline__ void fill_tw(float2* tw, int tid){
    #pragma unroll
    for (int k = tid; k < 512; k += 256){
        float s, c; sincosf(-(float)k * (TWO_PI_F/1024.0f), &s, &c);
        tw[k] = make_float2(c, s);
    }
}

// ---------- software grid barrier (sense-reversing) ----------
__device__ unsigned g_cnt = 0u;
__device__ unsigned g_gen = 0u;

__device__ __forceinline__ void gridbar(){
    __syncthreads();                 // all waves' stores drained (vmcnt0 before s_barrier)
    if (threadIdx.x == 0){
        __threadfence();             // publish this block's stores device-wide
        unsigned g = __hip_atomic_load(&g_gen, __ATOMIC_RELAXED, __HIP_MEMORY_SCOPE_AGENT);
        if (__hip_atomic_fetch_add(&g_cnt, 1u, __ATOMIC_ACQ_REL, __HIP_MEMORY_SCOPE_AGENT) == NB-1u){
            __hip_atomic_store(&g_cnt, 0u, __ATOMIC_RELAXED, __HIP_MEMORY_SCOPE_AGENT);
            __hip_atomic_fetch_add(&g_gen, 1u, __ATOMIC_RELEASE, __HIP_MEMORY_SCOPE_AGENT);
        } else {
            while (__hip_atomic_load(&g_gen, __ATOMIC_ACQUIRE, __HIP_MEMORY_SCOPE_AGENT) == g)
                __builtin_amdgcn_s_sleep(2);
        }
        __threadfence();             // invalidate stale lines before next phase's reads
    }
    __syncthreads();
}

// ---------- register phase kernels ----------
__device__ __forceinline__ void dif_ph1(float2 r[8], const float2* tw, int lane){
    float2 a, d;
    #pragma unroll
    for (int k=0;k<4;++k){
        a=r[k]; d=f2sub(r[k],r[k+4]);
        r[k]=f2add(a,r[k+4]);
        r[k+4]=cmulf(d, tw[lane+128*k]);
    }
    float2 w20 = tw[lane<<1], w21 = tw[(lane+128)<<1];
    a=r[0]; d=f2sub(r[0],r[2]); r[0]=f2add(a,r[2]); r[2]=cmulf(d,w20);
    a=r[1]; d=f2sub(r[1],r[3]); r[1]=f2add(a,r[3]); r[3]=cmulf(d,w21);
    a=r[4]; d=f2sub(r[4],r[6]); r[4]=f2add(a,r[6]); r[6]=cmulf(d,w20);
    a=r[5]; d=f2sub(r[5],r[7]); r[5]=f2add(a,r[7]); r[7]=cmulf(d,w21);
    float2 w3 = tw[lane<<2];
    a=r[0]; d=f2sub(r[0],r[1]); r[0]=f2add(a,r[1]); r[1]=cmulf(d,w3);
    a=r[2]; d=f2sub(r[2],r[3]); r[2]=f2add(a,r[3]); r[3]=cmulf(d,w3);
    a=r[4]; d=f2sub(r[4],r[5]); r[4]=f2add(a,r[5]); r[5]=cmulf(d,w3);
    a=r[6]; d=f2sub(r[6],r[7]); r[6]=f2add(a,r[7]); r[7]=cmulf(d,w3);
}
__device__ __forceinline__ void dit_ph1(float2 r[8], const float2* tw, int lane){
    float2 a, b;
    float2 w3 = tw[lane<<2];
    a=r[0]; b=cmulcj(r[1],w3); r[0]=f2add(a,b); r[1]=f2sub(a,b);
    a=r[2]; b=cmulcj(r[3],w3); r[2]=f2add(a,b); r[3]=f2sub(a,b);
    a=r[4]; b=cmulcj(r[5],w3); r[4]=f2add(a,b); r[5]=f2sub(a,b);
    a=r[6]; b=cmulcj(r[7],w3); r[6]=f2add(a,b); r[7]=f2sub(a,b);
    float2 w20 = tw[lane<<1], w21 = tw[(lane+128)<<1];
    a=r[0]; b=cmulcj(r[2],w20); r[0]=f2add(a,b); r[2]=f2sub(a,b);
    a=r[1]; b=cmulcj(r[3],w21); r[1]=f2add(a,b); r[3]=f2sub(a,b);
    a=r[4]; b=cmulcj(r[6],w20); r[4]=f2add(a,b); r[6]=f2sub(a,b);
    a=r[5]; b=cmulcj(r[7],w21); r[5]=f2add(a,b); r[7]=f2sub(a,b);
    #pragma unroll
    for (int k=0;k<4;++k){
        a=r[k]; b=cmulcj(r[k+4], tw[lane+128*k]);
        r[k]=f2add(a,b); r[k+4]=f2sub(a,b);
    }
}
__device__ __forceinline__ void dif_ph2(float2 r[8], const float2* tw, int m0){
    float2 a, d;
    #pragma unroll
    for (int k=0;k<4;++k){
        a=r[k]; d=f2sub(r[k],r[k+4]);
        r[k]=f2add(a,r[k+4]);
        r[k+4]=cmulf(d, tw[(m0+16*k)<<3]);
    }
    float2 w40 = tw[m0<<4], w41 = tw[(m0+16)<<4];
    a=r[0]; d=f2sub(r[0],r[2]); r[0]=f2add(a,r[2]); r[2]=cmulf(d,w40);
    a=r[1]; d=f2sub(r[1],r[3]); r[1]=f2add(a,r[3]); r[3]=cmulf(d,w41);
    a=r[4]; d=f2sub(r[4],r[6]); r[4]=f2add(a,r[6]); r[6]=cmulf(d,w40);
    a=r[5]; d=f2sub(r[5],r[7]); r[5]=f2add(a,r[7]); r[7]=cmulf(d,w41);
    float2 w5 = tw[m0<<5];
    a=r[0]; d=f2sub(r[0],r[1]); r[0]=f2add(a,r[1]); r[1]=cmulf(d,w5);
    a=r[2]; d=f2sub(r[2],r[3]); r[2]=f2add(a,r[3]); r[3]=cmulf(d,w5);
    a=r[4]; d=f2sub(r[4],r[5]); r[4]=f2add(a,r[5]); r[5]=cmulf(d,w5);
    a=r[6]; d=f2sub(r[6],r[7]); r[6]=f2add(a,r[7]); r[7]=cmulf(d,w5);
}
__device__ __forceinline__ void dit_ph2(float2 r[8], const float2* tw, int m0){
    float2 a, b;
    float2 w5 = tw[m0<<5];
    a=r[0]; b=cmulcj(r[1],w5); r[0]=f2add(a,b); r[1]=f2sub(a,b);
    a=r[2]; b=cmulcj(r[3],w5); r[2]=f2add(a,b); r[3]=f2sub(a,b);
    a=r[4]; b=cmulcj(r[5],w5); r[4]=f2add(a,b); r[5]=f2sub(a,b);
    a=r[6]; b=cmulcj(r[7],w5); r[6]=f2add(a,b); r[7]=f2sub(a,b);
    float2 w40 = tw[m0<<4], w41 = tw[(m0+16)<<4];
    a=r[0]; b=cmulcj(r[2],w40); r[0]=f2add(a,b); r[2]=f2sub(a,b);
    a=r[1]; b=cmulcj(r[3],w41); r[1]=f2add(a,b); r[3]=f2sub(a,b);
    a=r[4]; b=cmulcj(r[6],w40); r[4]=f2add(a,b); r[6]=f2sub(a,b);
    a=r[5]; b=cmulcj(r[7],w41); r[5]=f2add(a,b); r[7]=f2sub(a,b);
    #pragma unroll
    for (int k=0;k<4;++k){
        a=r[k]; b=cmulcj(r[k+4], tw[(m0+16*k)<<3]);
        r[k]=f2add(a,b); r[k+4]=f2sub(a,b);
    }
}
__device__ __forceinline__ void dif_reg(float2 r[8]){
    const float C = 0.70710678118654752f;
    float2 a,d;
    a=r[0]; d=f2sub(r[0],r[4]); r[0]=f2add(a,r[4]); r[4]=d;
    a=r[1]; d=f2sub(r[1],r[5]); r[1]=f2add(a,r[5]); r[5]=make_float2(C*(d.x+d.y), C*(d.y-d.x));
    a=r[2]; d=f2sub(r[2],r[6]); r[2]=f2add(a,r[6]); r[6]=make_float2(d.y, -d.x);
    a=r[3]; d=f2sub(r[3],r[7]); r[3]=f2add(a,r[7]); r[7]=make_float2(C*(d.y-d.x), -C*(d.x+d.y));
    a=r[0]; r[0]=f2add(a,r[2]); r[2]=f2sub(a,r[2]);
    a=r[1]; d=f2sub(r[1],r[3]); r[1]=f2add(a,r[3]); r[3]=make_float2(d.y,-d.x);
    a=r[4]; r[4]=f2add(a,r[6]); r[6]=f2sub(a,r[6]);
    a=r[5]; d=f2sub(r[5],r[7]); r[5]=f2add(a,r[7]); r[7]=make_float2(d.y,-d.x);
    a=r[0]; r[0]=f2add(a,r[1]); r[1]=f2sub(a,r[1]);
    a=r[2]; r[2]=f2add(a,r[3]); r[3]=f2sub(a,r[3]);
    a=r[4]; r[4]=f2add(a,r[5]); r[5]=f2sub(a,r[5]);
    a=r[6]; r[6]=f2add(a,r[7]); r[7]=f2sub(a,r[7]);
}
__device__ __forceinline__ void dit_reg(float2 r[8]){
    const float C = 0.70710678118654752f;
    float2 a,b,t;
    a=r[0]; r[0]=f2add(a,r[1]); r[1]=f2sub(a,r[1]);
    a=r[2]; r[2]=f2add(a,r[3]); r[3]=f2sub(a,r[3]);
    a=r[4]; r[4]=f2add(a,r[5]); r[5]=f2sub(a,r[5]);
    a=r[6]; r[6]=f2add(a,r[7]); r[7]=f2sub(a,r[7]);
    a=r[0]; r[0]=f2add(a,r[2]); r[2]=f2sub(a,r[2]);
    a=r[1]; t=r[3]; b=make_float2(-t.y, t.x); r[1]=f2add(a,b); r[3]=f2sub(a,b);
    a=r[4]; r[4]=f2add(a,r[6]); r[6]=f2sub(a,r[6]);
    a=r[5]; t=r[7]; b=make_float2(-t.y, t.x); r[5]=f2add(a,b); r[7]=f2sub(a,b);
    a=r[0]; r[0]=f2add(a,r[4]); r[4]=f2sub(a,r[4]);
    a=r[1]; t=r[5]; b=make_float2(C*(t.x-t.y), C*(t.x+t.y)); r[1]=f2add(a,b); r[5]=f2sub(a,b);
    a=r[2]; t=r[6]; b=make_float2(-t.y, t.x); r[2]=f2add(a,b); r[6]=f2sub(a,b);
    a=r[3]; t=r[7]; b=make_float2(-C*(t.x+t.y), C*(t.x-t.y)); r[3]=f2add(a,b); r[7]=f2sub(a,b);
}

// ---------- LDS exchange helpers ----------
__device__ __forceinline__ void st128l(float2* L, int ro, int lane, const float2 r[8]){
    #pragma unroll
    for (int k=0;k<8;++k) L[F(ro + lane + 128*k)] = r[k];
}
__device__ __forceinline__ void ld128l(const float2* L, int ro, int lane, float2 r[8]){
    #pragma unroll
    for (int k=0;k<8;++k) r[k] = L[F(ro + lane + 128*k)];
}
__device__ __forceinline__ void st16l(float2* L, int ro, int lane, const float2 r[8]){
    int b = lane>>4, m0 = lane&15, q = ro + 128*b + m0;
    #pragma unroll
    for (int k=0;k<8;++k) L[F(q + 16*k)] = r[k];
}
__device__ __forceinline__ void ld16l(const float2* L, int ro, int lane, float2 r[8]){
    int b = lane>>4, m0 = lane&15, q = ro + 128*b + m0;
    #pragma unroll
    for (int k=0;k<8;++k) r[k] = L[F(q + 16*k)];
}
__device__ __forceinline__ void st8l(float2* L, int ro, int lane, const float2 r[8]){
    int q = ro + 8*lane;
    #pragma unroll
    for (int i=0;i<8;++i) L[F(q + i)] = r[i];
}
__device__ __forceinline__ void ldfold_dif(const float2* L, int ro, int lane,
                                           const float2* tw, float2 r[8]){
    int rr = lane>>1, sub = lane&1, q = ro + 16*rr;
    #pragma unroll
    for (int i=0;i<8;++i){
        float2 x = L[F(q + i)];
        float2 y = L[F(q + 8 + i)];
        r[i] = sub ? cmulf(f2sub(x,y), tw[i<<6]) : f2add(x,y);
    }
}
__device__ __forceinline__ void ldfold_dit(const float2* L, int ro, int lane,
                                           const float2* tw, float2 r[8]){
    int b = lane>>4, m0 = lane&15, m0s = m0&7;
    float2 w = tw[m0s<<6];
    int q = ro + 128*b + m0s;
    #pragma unroll
    for (int k=0;k<8;++k){
        float2 x = L[F(q + 16*k)];
        float2 y = L[F(q + 16*k + 8)];
        float2 bb = cmulcj(y, w);
        r[k] = (m0 < 8) ? f2add(x,bb) : f2sub(x,bb);
    }
}
__device__ __forceinline__ void load8g(const float2* src, int lane, float2 r[8]){
    const float4* s4 = (const float4*)src + lane*4;
    #pragma unroll
    for (int m=0;m<4;++m){
        float4 v = s4[m];
        r[2*m]   = make_float2(v.x, v.y);
        r[2*m+1] = make_float2(v.z, v.w);
    }
}
__device__ __forceinline__ void twrite2(const float2* L, int tid, float2* dst,
                                        int r0, float s){
    #pragma unroll
    for (int k=0;k<4;++k){
        int c = tid + (k<<8);
        float2 a0 = L[F(c)], a1 = L[F(1024+c)];
        ((float4*)(dst + ((size_t)c<<10) + r0))[0] =
            make_float4(a0.x*s, a0.y*s, a1.x*s, a1.y*s);
    }
}

// ---------- chain phase bodies (verbatim from verified standalone kernels,
// minus per-dispatch fill_tw; tw is resident in LDS for the whole chain) ----
__device__ __forceinline__ void ph_head(float2* A, float2* B, const float2* tw,
    int tid, int row, int lane, int ro, int m0, int r0, size_t gbase,
    float2* dst, const float2* T0, const float* nail)
{
    float dfx = (float)DFX_D;
    float t0 = rintf(nail[0]*2.0f/dfx)*dfx;
    float t1 = rintf(nail[1]*2.0f/dfx)*dfx;
    float yv = (float)((r0+row) - 512) * 0.325f;
    float2 r[8];
    #pragma unroll
    for (int k=0;k<8;++k){
        int col = lane + 128*k;
        float2 tv = T0[gbase + col];
        float xv = (float)(col - 512) * 0.325f;
        float s0, c0; sincosf(TWO_PI_F*(t0*xv + t1*yv), &s0, &c0);
        r[k] = cmulf(make_float2(c0,s0), tv);
    }
    dif_ph1(r, tw, lane);
    st128l(A, ro, lane, r); __syncthreads();
    ld16l(A, ro, lane, r); dif_ph2(r, tw, m0);
    st16l(B, ro, lane, r); __syncthreads();
    ldfold_dif(B, ro, lane, tw, r); dif_reg(r);
    st8l(A, ro, lane, r); __syncthreads();
    twrite2(A, tid, dst, r0, 1.0f);
}

__device__ __forceinline__ void ph_p2(float2* A, float2* B, const float2* tw,
    int tid, int row, int lane, int ro, int m0, int r0,
    const float2* src, float2* dst, const float2* km, int conj, int pupil)
{
    const int jrow = r0 + row;
    const float2* srcR = src + (((size_t)r0)<<10) + ro;
    float2 r[8];
    #pragma unroll
    for (int k=0;k<8;++k) r[k] = srcR[lane + 128*k];
    float4 kv[4];
    if (!pupil){
        const float4* k4 = (const float4*)(km + (((size_t)jrow)<<10)) + lane*4;
        #pragma unroll
        for (int m=0;m<4;++m) kv[m] = k4[m];
    }
    dif_ph1(r, tw, lane);
    st128l(A, ro, lane, r); __syncthreads();
    ld16l(A, ro, lane, r); dif_ph2(r, tw, m0);
    st16l(B, ro, lane, r); __syncthreads();
    ldfold_dif(B, ro, lane, tw, r); dif_reg(r);
    if (pupil){
        int bb = __brev((unsigned)jrow) >> 22;
        int rb = bb - (bb >= 512 ? 1024 : 0);
        int rb2 = rb*rb;
        #pragma unroll
        for (int i=0;i<8;++i){
            int aa = __brev((unsigned)(8*lane+i)) >> 22;
            int ra = aa - (aa >= 512 ? 1024 : 0);
            if (ra*ra + rb2 > RRCUT) r[i] = make_float2(0.f,0.f);
        }
    } else {
        float sg = conj ? -1.0f : 1.0f;
        #pragma unroll
        for (int m=0;m<4;++m){
            r[2*m]   = cmulf(r[2*m],   make_float2(kv[m].x, sg*kv[m].y));
            r[2*m+1] = cmulf(r[2*m+1], make_float2(kv[m].z, sg*kv[m].w));
        }
    }
    dit_reg(r);
    st8l(A, ro, lane, r); __syncthreads();
    ldfold_dit(A, ro, lane, tw, r); dit_ph2(r, tw, m0);
    st16l(B, ro, lane, r); __syncthreads();
    ld128l(B, ro, lane, r); dit_ph1(r, tw, lane);
    st128l(A, ro, lane, r); __syncthreads();
    twrite2(A, tid, dst, r0, 1.0f/1024.0f);
}

__device__ __forceinline__ void ph_junc(float2* A, float2* B, const float2* tw,
    int tid, int row, int lane, int ro, int m0, int r0, size_t gbase,
    const float2* src, float2* dst, const float2* Tz, float2* wp,
    const float* meas, int mode)
{
    const float S = 1.0f/1024.0f;
    float2 r[8];
    load8g(src + (((size_t)r0)<<10) + ro, lane, r);
    float2 pre[8];
    if (mode == JT || mode == JT_WP){
        #pragma unroll
        for (int k=0;k<8;++k) pre[k] = Tz[gbase + lane + 128*k];
    } else if (mode == JRESID){
        #pragma unroll
        for (int k=0;k<8;++k) pre[k].x = meas[gbase + lane + 128*k];
    }
    dit_reg(r);
    st8l(A, ro, lane, r); __syncthreads();
    ldfold_dit(A, ro, lane, tw, r); dit_ph2(r, tw, m0);
    st16l(B, ro, lane, r); __syncthreads();
    ld128l(B, ro, lane, r); dit_ph1(r, tw, lane);
    #pragma unroll
    for (int k=0;k<8;++k){
        size_t g = gbase + lane + 128*k;
        float2 v = make_float2(S*r[k].x, S*r[k].y);
        if (mode == JT || mode == JT_WP){
            v = cmulf(v, pre[k]);
            if (mode == JT_WP) wp[g] = v;
        } else if (mode == JRESID){
            float m = pre[k].x;
            float aamp = fmaxf(sqrtf(v.x*v.x + v.y*v.y), 1e-30f);
            float f = 1.0f - sqrtf(m)/aamp;
            v.x *= f; v.y *= f;
        }
        r[k] = v;
    }
    dif_ph1(r, tw, lane);
    st128l(A, ro, lane, r); __syncthreads();
    ld16l(A, ro, lane, r); dif_ph2(r, tw, m0);
    st16l(B, ro, lane, r); __syncthreads();
    ldfold_dif(B, ro, lane, tw, r); dif_reg(r);
    st8l(A, ro, lane, r); __syncthreads();
    twrite2(A, tid, dst, r0, 1.0f);
}

__device__ __forceinline__ void ph_rev(float2* A, float2* B, const float2* tw,
    int tid, int row, int lane, int ro, int m0, int r0, size_t gbase,
    const float2* srcU, float2* dstU, const float2* srcB, float2* dstB,
    float2* Tz, int headU)
{
    const float S = 1.0f/1024.0f;
    float2 u[8], Tg[8], bb[8], r[8];
    if (!headU){
        load8g(srcU + (((size_t)r0)<<10) + ro, lane, u);
    } else {
        const float2* srcR = srcU + (((size_t)r0)<<10) + ro;
        #pragma unroll
        for (int k=0;k<8;++k) u[k] = srcR[lane + 128*k];
    }
    #pragma unroll
    for (int k=0;k<8;++k) Tg[k] = Tz[gbase + lane + 128*k];
    load8g(srcB + (((size_t)r0)<<10) + ro, lane, bb);
    if (!headU){
        dit_reg(u);
        st8l(A, ro, lane, u); __syncthreads();
        ldfold_dit(A, ro, lane, tw, u); dit_ph2(u, tw, m0);
        st16l(B, ro, lane, u); __syncthreads();
        ld128l(B, ro, lane, u); dit_ph1(u, tw, lane);
        #pragma unroll
        for (int k=0;k<8;++k){ u[k].x *= S; u[k].y *= S; }
    }
    #pragma unroll
    for (int k=0;k<8;++k){
        if (headU) r[k] = u[k];
        else {
            float inv = 1.0f/(Tg[k].x*Tg[k].x + Tg[k].y*Tg[k].y);
            float2 wc = cmulcj(u[k], Tg[k]);
            r[k] = make_float2(wc.x*inv, wc.y*inv);
        }
    }
    dif_ph1(r, tw, lane);
    st128l(A, ro, lane, r); __syncthreads();
    ld16l(A, ro, lane, r); dif_ph2(r, tw, m0);
    st16l(B, ro, lane, r); __syncthreads();
    ldfold_dif(B, ro, lane, tw, r); dif_reg(r);
    st8l(A, ro, lane, r); __syncthreads();
    twrite2(A, tid, dstU, r0, 1.0f);
    dit_reg(bb);
    st8l(B, ro, lane, bb); __syncthreads();
    ldfold_dit(B, ro, lane, tw, r); dit_ph2(r, tw, m0);
    st16l(A, ro, lane, r); __syncthreads();
    ld128l(A, ro, lane, r); dit_ph1(r, tw, lane);
    #pragma unroll
    for (int k=0;k<8;++k){
        float2 b = make_float2(S*r[k].x, S*r[k].y);
        float2 q = headU ? cmulcj(cmulcj(b, u[k]), Tg[k]) : cmulcj(b, u[k]);
        Tz[gbase + lane + 128*k] = make_float2(KAPPA*q.y, -KAPPA*q.x);
        r[k] = cmulcj(b, Tg[k]);
    }
    dif_ph1(r, tw, lane);
    st128l(B, ro, lane, r); __syncthreads();
    ld16l(B, ro, lane, r); dif_ph2(r, tw, m0);
    st16l(A, ro, lane, r); __syncthreads();
    ldfold_dif(A, ro, lane, tw, r); dif_reg(r);
    st8l(B, ro, lane, r); __syncthreads();
    twrite2(B, tid, dstB, r0, 1.0f);
}

__device__ __forceinline__ void ph_tail(float2* A, float2* B, const float2* tw,
    int tid, int row, int lane, int ro, int m0, int r0, size_t gbase,
    const float2* srcU, const float2* srcB, float2* G0)
{
    const float S = 1.0f/1024.0f;
    float2 u[8], r[8];
    load8g(srcU + (((size_t)r0)<<10) + ro, lane, u);
    load8g(srcB + (((size_t)r0)<<10) + ro, lane, r);
    dit_reg(u);
    st8l(A, ro, lane, u); __syncthreads();
    ldfold_dit(A, ro, lane, tw, u); dit_ph2(u, tw, m0);
    st16l(B, ro, lane, u); __syncthreads();
    ld128l(B, ro, lane, u); dit_ph1(u, tw, lane);
    dit_reg(r);
    st8l(A, ro, lane, r); __syncthreads();
    ldfold_dit(A, ro, lane, tw, r); dit_ph2(r, tw, m0);
    st16l(B, ro, lane, r); __syncthreads();
    ld128l(B, ro, lane, r); dit_ph1(r, tw, lane);
    #pragma unroll
    for (int k=0;k<8;++k){
        float2 b = make_float2(S*r[k].x, S*r[k].y);
        float2 w = make_float2(S*u[k].x, S*u[k].y);
        float2 q = cmulcj(b, w);
        G0[gbase + lane + 128*k] = make_float2(KAPPA*q.y, -KAPPA*q.x);
    }
}

// ---------- persistent chain kernel: 68 grid-barrier phases, 1 dispatch ----
// 512 blocks x 256 thr; LDS 38.9 KB -> 4 blocks/CU capacity, 2 needed (2x
// slack); __launch_bounds__(256,2) caps VGPR<=256 so 2 blocks/CU always fit.
__global__ void __launch_bounds__(256,2) k_chain(
    float2* T, const float2* KP, const float2* KF, float2* U0,
    float2* TAB, float2* TBB, float2* TAU, float2* TBU,
    const float* nail, const float* meas)
{
    __shared__ float2 A[2176], B[2176], tw[512];
    const int tid = threadIdx.x;
    fill_tw(tw, tid);
    const int row = tid>>7, lane = tid&127, ro = row<<10, m0 = lane&15;
    const int r0 = blockIdx.x*2;
    const size_t gbase = ((size_t)(r0+row))<<10;
    __syncthreads();                       // tw ready for the whole chain

    // ---- forward chain: head; then 19x (junc?, p2) ----
    ph_head(A,B,tw,tid,row,lane,ro,m0,r0,gbase, TAB, T, nail);
    gridbar();
    for (int s = 0; s <= 18; ++s){
        if (s > 0){
            int mode = (s<=14) ? JT : ((s==15) ? JT_WP : ((s==17) ? JRESID : JN));
            const float2* Tz = (s<=15) ? T + (size_t)s*NN : nullptr;
            float2* wp = (s==15) ? U0 : nullptr;
            const float* ms = (s==17) ? meas : nullptr;
            ph_junc(A,B,tw,tid,row,lane,ro,m0,r0,gbase, TBB, TAB, Tz, wp, ms, mode);
            gridbar();
        }
        const float2* km = (s<=14) ? KP : ((s==15 || s==18) ? KF : nullptr);
        int cj  = (s>=17) ? 1 : 0;
        int pup = (s==16 || s==17) ? 1 : 0;
        ph_p2(A,B,tw,tid,row,lane,ro,m0,r0, TAB, TBB, km, cj, pup);
        gridbar();
    }

    // ---- reverse loop: rev + (p2 on B pair, p2 on U pair) ----
    for (int zz = 15; zz >= 1; --zz){
        ph_rev(A,B,tw,tid,row,lane,ro,m0,r0,gbase,
               (zz==15) ? U0 : TBU, TAU, TBB, TAB, T + (size_t)zz*NN, (zz==15) ? 1 : 0);
        gridbar();
        #pragma unroll 1
        for (int un = 0; un < 2; ++un){
            ph_p2(A,B,tw,tid,row,lane,ro,m0,r0,
                  un ? TAU : TAB, un ? TBU : TBB, KP, 1, 0);
            if (!un) __syncthreads();
        }
        gridbar();
    }
    ph_tail(A,B,tw,tid,row,lane,ro,m0,r0,gbase, TBU, TBB, T);
}

// ---------- precompute kernels ----------
__global__ void __launch_bounds__(256) k_kern(float2* __restrict__ kp,
                                              float2* __restrict__ kf){
    int idx = blockIdx.x*256 + threadIdx.x;
    int j = idx >> 10, i = idx & 1023;
    int a = __brev((unsigned)i) >> 22;
    int b = __brev((unsigned)j) >> 22;
    int ra = a - (a >= 512 ? 1024 : 0);
    int rb = b - (b >= 512 ? 1024 : 0);
    int rr = ra*ra + rb*rb;
    float2 p = make_float2(0.f,0.f), f = make_float2(0.f,0.f);
    if (rr <= RRCUT){
        double urr = (double)rr * (DFX_D*DFX_D);
        double kz = sqrt(4.0 - urr);
        double t1 =  3.25    * kz;          // phase / 2*pi, reduced in double
        double t2 = -24.375  * kz;
        float f1 = (float)(t1 - floor(t1));
        float f2 = (float)(t2 - floor(t2));
        float s1,c1,s2,c2;
        sincosf(TWO_PI_F*f1, &s1, &c1);
        sincosf(TWO_PI_F*f2, &s2, &c2);
        p = make_float2(c1,s1);
        f = make_float2(c2,s2);
    }
    kp[idx] = p; kf[idx] = f;
}

// k_T: one thread per (pixel-pair, z-quad); 64 B in / 64 B out, float4 stores.
__global__ void __launch_bounds__(256) k_T(const float4* __restrict__ x,
                                           float2* __restrict__ T){
    int idx = blockIdx.x*256 + threadIdx.x;    // 0 .. 2M-1
    int pp = idx >> 2;                         // pixel pair
    int q  = idx & 3;                          // z-quad
    int p0 = pp*2;
    float4 vr0 = x[(size_t)p0*8 + q];
    float4 vi0 = x[(size_t)p0*8 + 4 + q];
    float4 vr1 = x[(size_t)(p0+1)*8 + q];
    float4 vi1 = x[(size_t)(p0+1)*8 + 4 + q];
    const float* fr0 = (const float*)&vr0;
    const float* fi0 = (const float*)&vi0;
    const float* fr1 = (const float*)&vr1;
    const float* fi1 = (const float*)&vi1;
    #pragma unroll
    for (int j=0;j<4;++j){
        int z = 4*q + j;
        float a0 = __expf(-KAPPA*fi0[j]);
        float s0, c0; __sincosf(KAPPA*fr0[j], &s0, &c0);
        float a1 = __expf(-KAPPA*fi1[j]);
        float s1, c1; __sincosf(KAPPA*fr1[j], &s1, &c1);
        ((float4*)(T + (size_t)z*NN + p0))[0] = make_float4(a0*c0, a0*s0, a1*c1, a1*s1);
    }
}

// k_merge: one thread per (pixel, z-quad) handling real+imag float4s; the 4
// G loads are shared between both outputs.
__global__ void __launch_bounds__(256) k_merge(const float4* __restrict__ x,
                                               const float2* __restrict__ G,
                                               const float* __restrict__ alpha,
                                               float4* __restrict__ out){
    int idx = blockIdx.x*256 + threadIdx.x;    // 0 .. 4M-1
    int p = idx >> 2, q = idx & 3;
    float al = alpha[0];
    float4 xr = x[(size_t)p*8 + q];
    float4 xi = x[(size_t)p*8 + 4 + q];
    float2 g[4];
    #pragma unroll
    for (int j=0;j<4;++j) g[j] = G[(size_t)(4*q+j)*NN + p];
    out[(size_t)p*8 + q]     = make_float4(xr.x - al*g[0].x, xr.y - al*g[1].x,
                                           xr.z - al*g[2].x, xr.w - al*g[3].x);
    out[(size_t)p*8 + 4 + q] = make_float4(xi.x - al*g[0].y, xi.y - al*g[1].y,
                                           xi.z - al*g[2].y, xi.w - al*g[3].y);
}

extern "C" void kernel_launch(void* const* d_in, const int* in_sizes, int n_in,
                              void* d_out, int out_size, void* d_ws, size_t ws_size,
                              hipStream_t stream)
{
    const float* x     = (const float*)d_in[0];
    const float* meas  = (const float*)d_in[1];
    const float* nail  = (const float*)d_in[2];
    const float* alpha = (const float*)d_in[3];

    if (ws_size < (size_t)23*NN*sizeof(float2)) return;

    float2* W   = (float2*)d_ws;
    float2* T   = W;                       // 16 planes; grads overwrite in place
    float2* KP  = W + (size_t)16*NN;
    float2* KF  = W + (size_t)17*NN;
    float2* U0  = W + (size_t)18*NN;
    float2* TAB = W + (size_t)19*NN;
    float2* TBB = W + (size_t)20*NN;
    float2* TAU = W + (size_t)21*NN;
    float2* TBU = W + (size_t)22*NN;

    k_kern <<<4096, 256, 0, stream>>>(KP, KF);
    k_T    <<<8192, 256, 0, stream>>>((const float4*)x, T);
    k_chain<<<512,  256, 0, stream>>>(T, KP, KF, U0, TAB, TBB, TAU, TBU, nail, meas);
    k_merge<<<16384,256, 0, stream>>>((const float4*)x, T, alpha, (float4*)d_out);
}

// Round 3
// 1421.410 us; speedup vs baseline: 6.0066x; 6.0066x over previous
//
#include <hip/hip_runtime.h>
#include <math.h>

// Multislice gradient step. 1024-pt complex fp32 FFT as 3 register-radix-8
// phases (fused radix-2 stages 0-2 / 3-5 / 6-9) with ping-pong LDS exchanges.
// R3 (from R1 multi-dispatch base; persistent-kernel R2 reverted — cross-XCD
// fences destroyed cache residency):
//  - pupil section collapsed algebraically: KF already contains the pupil
//    mask (PC^2 = PC) and row-IFFT+row-FFT (JN junc) is identity, so the two
//    pupil p2 passes + two JN juncs are exact no-ops. 4 dispatches deleted.
//  - KP/KF computed inline in p2 (same fp64-frac + fp32 sincosf math as the
//    verified k_kern); k_kern dispatch and all kernel-image reads removed.
//  - coalesced k_T / k_merge kept from R2.

#define NN (1024*1024)
#define KAPPA 40.840704496667314f
#define TWO_PI_F 6.2831853071795865f
#define DFX_D 0.0030048076923076925
#define RRCUT 187177
#define F(i) ((i) + ((i)>>4))

#define JT 0
#define JT_WP 1
#define JRESID 3

__device__ __forceinline__ float2 cmulf(float2 a, float2 b){
    return make_float2(a.x*b.x - a.y*b.y, a.x*b.y + a.y*b.x);
}
__device__ __forceinline__ float2 cmulcj(float2 a, float2 b){ // a * conj(b)
    return make_float2(a.x*b.x + a.y*b.y, a.y*b.x - a.x*b.y);
}
__device__ __forceinline__ float2 f2add(float2 a, float2 b){ return make_float2(a.x+b.x, a.y+b.y); }
__device__ __forceinline__ float2 f2sub(float2 a, float2 b){ return make_float2(a.x-b.x, a.y-b.y); }

__device__ __forceinline__ void fill_tw(float2* tw, int tid){
    #pragma unroll
    for (int k = tid; k < 512; k += 256){
        float s, c; sincosf(-(float)k * (TWO_PI_F/1024.0f), &s, &c);
        tw[k] = make_float2(c, s);
    }
}

// ---------- register phase kernels (positions tracked per comments) ----------
// DIF phase1: stages half=512,256,128 on elements at positions lane+128k
__device__ __forceinline__ void dif_ph1(float2 r[8], const float2* tw, int lane){
    float2 a, d;
    #pragma unroll
    for (int k=0;k<4;++k){
        a=r[k]; d=f2sub(r[k],r[k+4]);
        r[k]=f2add(a,r[k+4]);
        r[k+4]=cmulf(d, tw[lane+128*k]);
    }
    float2 w20 = tw[lane<<1], w21 = tw[(lane+128)<<1];
    a=r[0]; d=f2sub(r[0],r[2]); r[0]=f2add(a,r[2]); r[2]=cmulf(d,w20);
    a=r[1]; d=f2sub(r[1],r[3]); r[1]=f2add(a,r[3]); r[3]=cmulf(d,w21);
    a=r[4]; d=f2sub(r[4],r[6]); r[4]=f2add(a,r[6]); r[6]=cmulf(d,w20);
    a=r[5]; d=f2sub(r[5],r[7]); r[5]=f2add(a,r[7]); r[7]=cmulf(d,w21);
    float2 w3 = tw[lane<<2];
    a=r[0]; d=f2sub(r[0],r[1]); r[0]=f2add(a,r[1]); r[1]=cmulf(d,w3);
    a=r[2]; d=f2sub(r[2],r[3]); r[2]=f2add(a,r[3]); r[3]=cmulf(d,w3);
    a=r[4]; d=f2sub(r[4],r[5]); r[4]=f2add(a,r[5]); r[5]=cmulf(d,w3);
    a=r[6]; d=f2sub(r[6],r[7]); r[6]=f2add(a,r[7]); r[7]=cmulf(d,w3);
}
// DIT phase1': stages half=128,256,512 (inverse of dif_ph1)
__device__ __forceinline__ void dit_ph1(float2 r[8], const float2* tw, int lane){
    float2 a, b;
    float2 w3 = tw[lane<<2];
    a=r[0]; b=cmulcj(r[1],w3); r[0]=f2add(a,b); r[1]=f2sub(a,b);
    a=r[2]; b=cmulcj(r[3],w3); r[2]=f2add(a,b); r[3]=f2sub(a,b);
    a=r[4]; b=cmulcj(r[5],w3); r[4]=f2add(a,b); r[5]=f2sub(a,b);
    a=r[6]; b=cmulcj(r[7],w3); r[6]=f2add(a,b); r[7]=f2sub(a,b);
    float2 w20 = tw[lane<<1], w21 = tw[(lane+128)<<1];
    a=r[0]; b=cmulcj(r[2],w20); r[0]=f2add(a,b); r[2]=f2sub(a,b);
    a=r[1]; b=cmulcj(r[3],w21); r[1]=f2add(a,b); r[3]=f2sub(a,b);
    a=r[4]; b=cmulcj(r[6],w20); r[4]=f2add(a,b); r[6]=f2sub(a,b);
    a=r[5]; b=cmulcj(r[7],w21); r[5]=f2add(a,b); r[7]=f2sub(a,b);
    #pragma unroll
    for (int k=0;k<4;++k){
        a=r[k]; b=cmulcj(r[k+4], tw[lane+128*k]);
        r[k]=f2add(a,b); r[k+4]=f2sub(a,b);
    }
}
// DIF phase2: stages half=64,32,16 on elements at positions 128b+m0+16k
__device__ __forceinline__ void dif_ph2(float2 r[8], const float2* tw, int m0){
    float2 a, d;
    #pragma unroll
    for (int k=0;k<4;++k){
        a=r[k]; d=f2sub(r[k],r[k+4]);
        r[k]=f2add(a,r[k+4]);
        r[k+4]=cmulf(d, tw[(m0+16*k)<<3]);
    }
    float2 w40 = tw[m0<<4], w41 = tw[(m0+16)<<4];
    a=r[0]; d=f2sub(r[0],r[2]); r[0]=f2add(a,r[2]); r[2]=cmulf(d,w40);
    a=r[1]; d=f2sub(r[1],r[3]); r[1]=f2add(a,r[3]); r[3]=cmulf(d,w41);
    a=r[4]; d=f2sub(r[4],r[6]); r[4]=f2add(a,r[6]); r[6]=cmulf(d,w40);
    a=r[5]; d=f2sub(r[5],r[7]); r[5]=f2add(a,r[7]); r[7]=cmulf(d,w41);
    float2 w5 = tw[m0<<5];
    a=r[0]; d=f2sub(r[0],r[1]); r[0]=f2add(a,r[1]); r[1]=cmulf(d,w5);
    a=r[2]; d=f2sub(r[2],r[3]); r[2]=f2add(a,r[3]); r[3]=cmulf(d,w5);
    a=r[4]; d=f2sub(r[4],r[5]); r[4]=f2add(a,r[5]); r[5]=cmulf(d,w5);
    a=r[6]; d=f2sub(r[6],r[7]); r[6]=f2add(a,r[7]); r[7]=cmulf(d,w5);
}
// DIT phase2': stages half=16,32,64
__device__ __forceinline__ void dit_ph2(float2 r[8], const float2* tw, int m0){
    float2 a, b;
    float2 w5 = tw[m0<<5];
    a=r[0]; b=cmulcj(r[1],w5); r[0]=f2add(a,b); r[1]=f2sub(a,b);
    a=r[2]; b=cmulcj(r[3],w5); r[2]=f2add(a,b); r[3]=f2sub(a,b);
    a=r[4]; b=cmulcj(r[5],w5); r[4]=f2add(a,b); r[5]=f2sub(a,b);
    a=r[6]; b=cmulcj(r[7],w5); r[6]=f2add(a,b); r[7]=f2sub(a,b);
    float2 w40 = tw[m0<<4], w41 = tw[(m0+16)<<4];
    a=r[0]; b=cmulcj(r[2],w40); r[0]=f2add(a,b); r[2]=f2sub(a,b);
    a=r[1]; b=cmulcj(r[3],w41); r[1]=f2add(a,b); r[3]=f2sub(a,b);
    a=r[4]; b=cmulcj(r[6],w40); r[4]=f2add(a,b); r[6]=f2sub(a,b);
    a=r[5]; b=cmulcj(r[7],w41); r[5]=f2add(a,b); r[7]=f2sub(a,b);
    #pragma unroll
    for (int k=0;k<4;++k){
        a=r[k]; b=cmulcj(r[k+4], tw[(m0+16*k)<<3]);
        r[k]=f2add(a,b); r[k+4]=f2sub(a,b);
    }
}
// radix-8 tail: DIF stages half=4,2,1 on 8 consecutive elems (verified R2)
__device__ __forceinline__ void dif_reg(float2 r[8]){
    const float C = 0.70710678118654752f;
    float2 a,d;
    a=r[0]; d=f2sub(r[0],r[4]); r[0]=f2add(a,r[4]); r[4]=d;
    a=r[1]; d=f2sub(r[1],r[5]); r[1]=f2add(a,r[5]); r[5]=make_float2(C*(d.x+d.y), C*(d.y-d.x));
    a=r[2]; d=f2sub(r[2],r[6]); r[2]=f2add(a,r[6]); r[6]=make_float2(d.y, -d.x);
    a=r[3]; d=f2sub(r[3],r[7]); r[3]=f2add(a,r[7]); r[7]=make_float2(C*(d.y-d.x), -C*(d.x+d.y));
    a=r[0]; r[0]=f2add(a,r[2]); r[2]=f2sub(a,r[2]);
    a=r[1]; d=f2sub(r[1],r[3]); r[1]=f2add(a,r[3]); r[3]=make_float2(d.y,-d.x);
    a=r[4]; r[4]=f2add(a,r[6]); r[6]=f2sub(a,r[6]);
    a=r[5]; d=f2sub(r[5],r[7]); r[5]=f2add(a,r[7]); r[7]=make_float2(d.y,-d.x);
    a=r[0]; r[0]=f2add(a,r[1]); r[1]=f2sub(a,r[1]);
    a=r[2]; r[2]=f2add(a,r[3]); r[3]=f2sub(a,r[3]);
    a=r[4]; r[4]=f2add(a,r[5]); r[5]=f2sub(a,r[5]);
    a=r[6]; r[6]=f2add(a,r[7]); r[7]=f2sub(a,r[7]);
}
// radix-8 head: DIT stages half=1,2,4 (verified R2)
__device__ __forceinline__ void dit_reg(float2 r[8]){
    const float C = 0.70710678118654752f;
    float2 a,b,t;
    a=r[0]; r[0]=f2add(a,r[1]); r[1]=f2sub(a,r[1]);
    a=r[2]; r[2]=f2add(a,r[3]); r[3]=f2sub(a,r[3]);
    a=r[4]; r[4]=f2add(a,r[5]); r[5]=f2sub(a,r[5]);
    a=r[6]; r[6]=f2add(a,r[7]); r[7]=f2sub(a,r[7]);
    a=r[0]; r[0]=f2add(a,r[2]); r[2]=f2sub(a,r[2]);
    a=r[1]; t=r[3]; b=make_float2(-t.y, t.x); r[1]=f2add(a,b); r[3]=f2sub(a,b);
    a=r[4]; r[4]=f2add(a,r[6]); r[6]=f2sub(a,r[6]);
    a=r[5]; t=r[7]; b=make_float2(-t.y, t.x); r[5]=f2add(a,b); r[7]=f2sub(a,b);
    a=r[0]; r[0]=f2add(a,r[4]); r[4]=f2sub(a,r[4]);
    a=r[1]; t=r[5]; b=make_float2(C*(t.x-t.y), C*(t.x+t.y)); r[1]=f2add(a,b); r[5]=f2sub(a,b);
    a=r[2]; t=r[6]; b=make_float2(-t.y, t.x); r[2]=f2add(a,b); r[6]=f2sub(a,b);
    a=r[3]; t=r[7]; b=make_float2(-C*(t.x+t.y), C*(t.x-t.y)); r[3]=f2add(a,b); r[7]=f2sub(a,b);
}

// ---------- LDS exchange helpers (ro = row*1024 position offset) ----------
__device__ __forceinline__ void st128l(float2* L, int ro, int lane, const float2 r[8]){
    #pragma unroll
    for (int k=0;k<8;++k) L[F(ro + lane + 128*k)] = r[k];
}
__device__ __forceinline__ void ld128l(const float2* L, int ro, int lane, float2 r[8]){
    #pragma unroll
    for (int k=0;k<8;++k) r[k] = L[F(ro + lane + 128*k)];
}
__device__ __forceinline__ void st16l(float2* L, int ro, int lane, const float2 r[8]){
    int b = lane>>4, m0 = lane&15, q = ro + 128*b + m0;
    #pragma unroll
    for (int k=0;k<8;++k) L[F(q + 16*k)] = r[k];
}
__device__ __forceinline__ void ld16l(const float2* L, int ro, int lane, float2 r[8]){
    int b = lane>>4, m0 = lane&15, q = ro + 128*b + m0;
    #pragma unroll
    for (int k=0;k<8;++k) r[k] = L[F(q + 16*k)];
}
__device__ __forceinline__ void st8l(float2* L, int ro, int lane, const float2 r[8]){
    int q = ro + 8*lane;
    #pragma unroll
    for (int i=0;i<8;++i) L[F(q + i)] = r[i];
}
// read after st8l state, fold DIF stage half=8, leaves 8 consecutive (pos 8*lane+i)
__device__ __forceinline__ void ldfold_dif(const float2* L, int ro, int lane,
                                           const float2* tw, float2 r[8]){
    int rr = lane>>1, sub = lane&1, q = ro + 16*rr;
    #pragma unroll
    for (int i=0;i<8;++i){
        float2 x = L[F(q + i)];
        float2 y = L[F(q + 8 + i)];
        r[i] = sub ? cmulf(f2sub(x,y), tw[i<<6]) : f2add(x,y);
    }
}
// read after st8l state, fold DIT stage half=8, leaves stride-16 (pos 128b+m0+16k)
__device__ __forceinline__ void ldfold_dit(const float2* L, int ro, int lane,
                                           const float2* tw, float2 r[8]){
    int b = lane>>4, m0 = lane&15, m0s = m0&7;
    float2 w = tw[m0s<<6];
    int q = ro + 128*b + m0s;
    #pragma unroll
    for (int k=0;k<8;++k){
        float2 x = L[F(q + 16*k)];
        float2 y = L[F(q + 16*k + 8)];
        float2 bb = cmulcj(y, w);
        r[k] = (m0 < 8) ? f2add(x,bb) : f2sub(x,bb);
    }
}
__device__ __forceinline__ void load8g(const float2* src, int lane, float2 r[8]){
    const float4* s4 = (const float4*)src + lane*4;
    #pragma unroll
    for (int m=0;m<4;++m){
        float4 v = s4[m];
        r[2*m]   = make_float2(v.x, v.y);
        r[2*m+1] = make_float2(v.z, v.w);
    }
}
__device__ __forceinline__ void twrite2(const float2* L, int tid, float2* dst,
                                        int r0, float s){
    #pragma unroll
    for (int k=0;k<4;++k){
        int c = tid + (k<<8);
        float2 a0 = L[F(c)], a1 = L[F(1024+c)];
        ((float4*)(dst + ((size_t)c<<10) + r0))[0] =
            make_float4(a0.x*s, a0.y*s, a1.x*s, a1.y*s);
    }
}

// ---------- chain head: u = planewave*T0, row DIF, transposed write ----------
__global__ void __launch_bounds__(256) k_head(float2* __restrict__ dst,
                                              const float2* __restrict__ T0,
                                              const float* __restrict__ nail){
    __shared__ float2 A[2176], B[2176], tw[512];
    const int tid = threadIdx.x;
    fill_tw(tw, tid);
    const int row = tid>>7, lane = tid&127, ro = row<<10, m0 = lane&15;
    const int r0 = blockIdx.x*2;
    const size_t gbase = ((size_t)(r0+row))<<10;
    float dfx = (float)DFX_D;
    float t0 = rintf(nail[0]*2.0f/dfx)*dfx;
    float t1 = rintf(nail[1]*2.0f/dfx)*dfx;
    float yv = (float)((r0+row) - 512) * 0.325f;
    float2 r[8];
    #pragma unroll
    for (int k=0;k<8;++k){
        int col = lane + 128*k;
        float2 tv = T0[gbase + col];
        float xv = (float)(col - 512) * 0.325f;
        float s0, c0; sincosf(TWO_PI_F*(t0*xv + t1*yv), &s0, &c0);
        r[k] = cmulf(make_float2(c0,s0), tv);
    }
    __syncthreads();                       // tw ready
    dif_ph1(r, tw, lane);
    st128l(A, ro, lane, r); __syncthreads();
    ld16l(A, ro, lane, r); dif_ph2(r, tw, m0);
    st16l(B, ro, lane, r); __syncthreads();
    ldfold_dif(B, ro, lane, tw, r); dif_reg(r);
    st8l(A, ro, lane, r); __syncthreads();
    twrite2(A, tid, dst, r0, 1.0f);
}

// ---------- pass2: col DIF + inline Fresnel-kernel mult (bitrev) + col DIT ----
// Kernel value computed on the fly (fp64 phase reduction + fp32 sincos, same
// math as the verified k_kern). zscale: 3.25 (KP) or -24.375 (KF); sg = -1
// applies conj. The pupil mask is rr<=RRCUT, already implied by the kernel.
__global__ void __launch_bounds__(256) k_pass2(
    const float2* __restrict__ srcA, float2* __restrict__ dstA,
    const float2* __restrict__ srcB, float2* __restrict__ dstB,
    double zscale, float sg)
{
    __shared__ float2 A[2176], B[2176], tw[512];
    const int tid = threadIdx.x;
    fill_tw(tw, tid);
    const int row = tid>>7, lane = tid&127, ro = row<<10, m0 = lane&15;
    int bid = blockIdx.x;
    const float2* src = srcA; float2* dst = dstA;
    if (srcB != nullptr && bid >= 512){ src = srcB; dst = dstB; bid -= 512; }
    const int r0 = bid*2;
    const int jrow = r0 + row;
    const float2* srcR = src + (((size_t)r0)<<10) + ro;
    float2 r[8];
    #pragma unroll
    for (int k=0;k<8;++k) r[k] = srcR[lane + 128*k];
    __syncthreads();                       // tw ready
    dif_ph1(r, tw, lane);
    st128l(A, ro, lane, r); __syncthreads();
    ld16l(A, ro, lane, r); dif_ph2(r, tw, m0);
    st16l(B, ro, lane, r); __syncthreads();
    ldfold_dif(B, ro, lane, tw, r); dif_reg(r);
    // pointwise at bitrev positions 8*lane+i of row jrow
    {
        int bb = __brev((unsigned)jrow) >> 22;
        int rb = bb - (bb >= 512 ? 1024 : 0);
        int rb2 = rb*rb;
        #pragma unroll
        for (int i=0;i<8;++i){
            int aa = __brev((unsigned)(8*lane+i)) >> 22;
            int ra = aa - (aa >= 512 ? 1024 : 0);
            int rr = ra*ra + rb2;
            if (rr <= RRCUT){
                double urr = (double)rr * (DFX_D*DFX_D);
                double kz = sqrt(4.0 - urr);
                double t = zscale * kz;
                float fp = (float)(t - floor(t));
                float s, c; sincosf(TWO_PI_F*fp, &s, &c);
                r[i] = cmulf(r[i], make_float2(c, sg*s));
            } else {
                r[i] = make_float2(0.f, 0.f);
            }
        }
    }
    dit_reg(r);
    st8l(A, ro, lane, r); __syncthreads();
    ldfold_dit(A, ro, lane, tw, r); dit_ph2(r, tw, m0);
    st16l(B, ro, lane, r); __syncthreads();
    ld128l(B, ro, lane, r); dit_ph1(r, tw, lane);
    st128l(A, ro, lane, r); __syncthreads();
    twrite2(A, tid, dst, r0, 1.0f/1024.0f);
}

// ---------- fused junction: row DIT + pointwise + row DIF ----------
__global__ void __launch_bounds__(256) k_junc(
    const float2* __restrict__ src, float2* __restrict__ dst,
    const float2* __restrict__ Tz, float2* __restrict__ wp,
    const float* __restrict__ meas, int mode)
{
    __shared__ float2 A[2176], B[2176], tw[512];
    const int tid = threadIdx.x;
    fill_tw(tw, tid);
    const int row = tid>>7, lane = tid&127, ro = row<<10, m0 = lane&15;
    const int r0 = blockIdx.x*2;
    const size_t gbase = ((size_t)(r0+row))<<10;
    const float S = 1.0f/1024.0f;
    float2 r[8];
    load8g(src + (((size_t)r0)<<10) + ro, lane, r);
    // hoisted pointwise-operand prefetch (Tz or meas)
    float2 pre[8];
    if (mode == JT || mode == JT_WP){
        #pragma unroll
        for (int k=0;k<8;++k) pre[k] = Tz[gbase + lane + 128*k];
    } else if (mode == JRESID){
        #pragma unroll
        for (int k=0;k<8;++k) pre[k].x = meas[gbase + lane + 128*k];
    }
    dit_reg(r);
    st8l(A, ro, lane, r); __syncthreads();
    ldfold_dit(A, ro, lane, tw, r); dit_ph2(r, tw, m0);
    st16l(B, ro, lane, r); __syncthreads();
    ld128l(B, ro, lane, r); dit_ph1(r, tw, lane);
    #pragma unroll
    for (int k=0;k<8;++k){
        size_t g = gbase + lane + 128*k;
        float2 v = make_float2(S*r[k].x, S*r[k].y);
        if (mode == JT || mode == JT_WP){
            v = cmulf(v, pre[k]);
            if (mode == JT_WP) wp[g] = v;
        } else if (mode == JRESID){
            float m = pre[k].x;
            float aamp = fmaxf(sqrtf(v.x*v.x + v.y*v.y), 1e-30f);
            float f = 1.0f - sqrtf(m)/aamp;
            v.x *= f; v.y *= f;
        }
        r[k] = v;
    }
    dif_ph1(r, tw, lane);
    st128l(A, ro, lane, r); __syncthreads();
    ld16l(A, ro, lane, r); dif_ph2(r, tw, m0);
    st16l(B, ro, lane, r); __syncthreads();
    ldfold_dif(B, ro, lane, tw, r); dif_reg(r);
    st8l(A, ro, lane, r); __syncthreads();
    twrite2(A, tid, dst, r0, 1.0f);
}

// ---------- reverse junction: both chains per tile; grad -> T plane ----------
__global__ void __launch_bounds__(256) k_rev(
    const float2* __restrict__ srcU, float2* __restrict__ dstU,
    const float2* __restrict__ srcB, float2* __restrict__ dstB,
    float2* __restrict__ Tz, int headU)
{
    __shared__ float2 A[2176], B[2176], tw[512];
    const int tid = threadIdx.x;
    fill_tw(tw, tid);
    const int row = tid>>7, lane = tid&127, ro = row<<10, m0 = lane&15;
    const int r0 = blockIdx.x*2;
    const size_t gbase = ((size_t)(r0+row))<<10;
    const float S = 1.0f/1024.0f;
    float2 u[8], Tg[8], bb[8], r[8];
    // ---- issue ALL global loads up front (one latency window, not three) ----
    if (!headU){
        load8g(srcU + (((size_t)r0)<<10) + ro, lane, u);
    } else {
        const float2* srcR = srcU + (((size_t)r0)<<10) + ro;
        #pragma unroll
        for (int k=0;k<8;++k) u[k] = srcR[lane + 128*k];
    }
    #pragma unroll
    for (int k=0;k<8;++k) Tg[k] = Tz[gbase + lane + 128*k];
    load8g(srcB + (((size_t)r0)<<10) + ro, lane, bb);
    // ---- U chain: DIT (or direct natural load at head) ----
    if (!headU){
        dit_reg(u);
        st8l(A, ro, lane, u); __syncthreads();
        ldfold_dit(A, ro, lane, tw, u); dit_ph2(u, tw, m0);
        st16l(B, ro, lane, u); __syncthreads();
        ld128l(B, ro, lane, u); dit_ph1(u, tw, lane);
        #pragma unroll
        for (int k=0;k<8;++k){ u[k].x *= S; u[k].y *= S; }
    } else {
        __syncthreads();                   // tw ready for dif_ph1 below
    }
    // divided field (skip at head)
    #pragma unroll
    for (int k=0;k<8;++k){
        if (headU) r[k] = u[k];
        else {
            float inv = 1.0f/(Tg[k].x*Tg[k].x + Tg[k].y*Tg[k].y);
            float2 wc = cmulcj(u[k], Tg[k]);
            r[k] = make_float2(wc.x*inv, wc.y*inv);
        }
    }
    dif_ph1(r, tw, lane);
    st128l(A, ro, lane, r); __syncthreads();
    ld16l(A, ro, lane, r); dif_ph2(r, tw, m0);
    st16l(B, ro, lane, r); __syncthreads();
    ldfold_dif(B, ro, lane, tw, r); dif_reg(r);
    st8l(A, ro, lane, r); __syncthreads();
    twrite2(A, tid, dstU, r0, 1.0f);
    // ---- B chain: DIT (from prefetched bb) ----
    dit_reg(bb);
    st8l(B, ro, lane, bb); __syncthreads();
    ldfold_dit(B, ro, lane, tw, r); dit_ph2(r, tw, m0);
    st16l(A, ro, lane, r); __syncthreads();
    ld128l(A, ro, lane, r); dit_ph1(r, tw, lane);
    // grad emit (into T plane) + premult conj(T)
    #pragma unroll
    for (int k=0;k<8;++k){
        float2 b = make_float2(S*r[k].x, S*r[k].y);
        float2 q = headU ? cmulcj(cmulcj(b, u[k]), Tg[k]) : cmulcj(b, u[k]);
        Tz[gbase + lane + 128*k] = make_float2(KAPPA*q.y, -KAPPA*q.x);
        r[k] = cmulcj(b, Tg[k]);
    }
    dif_ph1(r, tw, lane);
    st128l(B, ro, lane, r); __syncthreads();
    ld16l(B, ro, lane, r); dif_ph2(r, tw, m0);
    st16l(A, ro, lane, r); __syncthreads();
    ldfold_dif(A, ro, lane, tw, r); dif_reg(r);
    st8l(B, ro, lane, r); __syncthreads();
    twrite2(B, tid, dstB, r0, 1.0f);
}

// ---------- tail: finish both chains, grad[0] -> T plane 0 ----------
__global__ void __launch_bounds__(256) k_tail(
    const float2* __restrict__ srcU, const float2* __restrict__ srcB,
    float2* __restrict__ G0)
{
    __shared__ float2 A[2176], B[2176], tw[512];
    const int tid = threadIdx.x;
    fill_tw(tw, tid);
    const int row = tid>>7, lane = tid&127, ro = row<<10, m0 = lane&15;
    const int r0 = blockIdx.x*2;
    const size_t gbase = ((size_t)(r0+row))<<10;
    const float S = 1.0f/1024.0f;
    float2 u[8], r[8];
    load8g(srcU + (((size_t)r0)<<10) + ro, lane, u);
    load8g(srcB + (((size_t)r0)<<10) + ro, lane, r);   // hoisted prefetch
    dit_reg(u);
    st8l(A, ro, lane, u); __syncthreads();
    ldfold_dit(A, ro, lane, tw, u); dit_ph2(u, tw, m0);
    st16l(B, ro, lane, u); __syncthreads();
    ld128l(B, ro, lane, u); dit_ph1(u, tw, lane);
    dit_reg(r);
    st8l(A, ro, lane, r); __syncthreads();
    ldfold_dit(A, ro, lane, tw, r); dit_ph2(r, tw, m0);
    st16l(B, ro, lane, r); __syncthreads();
    ld128l(B, ro, lane, r); dit_ph1(r, tw, lane);
    #pragma unroll
    for (int k=0;k<8;++k){
        float2 b = make_float2(S*r[k].x, S*r[k].y);
        float2 w = make_float2(S*u[k].x, S*u[k].y);
        float2 q = cmulcj(b, w);
        G0[gbase + lane + 128*k] = make_float2(KAPPA*q.y, -KAPPA*q.x);
    }
}

// k_T: one thread per (pixel-pair, z-quad); 64 B in / 64 B out, float4 stores.
__global__ void __launch_bounds__(256) k_T(const float4* __restrict__ x,
                                           float2* __restrict__ T){
    int idx = blockIdx.x*256 + threadIdx.x;    // 0 .. 2M-1
    int pp = idx >> 2;                         // pixel pair
    int q  = idx & 3;                          // z-quad
    int p0 = pp*2;
    float4 vr0 = x[(size_t)p0*8 + q];
    float4 vi0 = x[(size_t)p0*8 + 4 + q];
    float4 vr1 = x[(size_t)(p0+1)*8 + q];
    float4 vi1 = x[(size_t)(p0+1)*8 + 4 + q];
    const float* fr0 = (const float*)&vr0;
    const float* fi0 = (const float*)&vi0;
    const float* fr1 = (const float*)&vr1;
    const float* fi1 = (const float*)&vi1;
    #pragma unroll
    for (int j=0;j<4;++j){
        int z = 4*q + j;
        float a0 = __expf(-KAPPA*fi0[j]);
        float s0, c0; __sincosf(KAPPA*fr0[j], &s0, &c0);
        float a1 = __expf(-KAPPA*fi1[j]);
        float s1, c1; __sincosf(KAPPA*fr1[j], &s1, &c1);
        ((float4*)(T + (size_t)z*NN + p0))[0] = make_float4(a0*c0, a0*s0, a1*c1, a1*s1);
    }
}

// k_merge: one thread per (pixel, z-quad) handling real+imag float4s; the 4
// G loads are shared between both outputs.
__global__ void __launch_bounds__(256) k_merge(const float4* __restrict__ x,
                                               const float2* __restrict__ G,
                                               const float* __restrict__ alpha,
                                               float4* __restrict__ out){
    int idx = blockIdx.x*256 + threadIdx.x;    // 0 .. 4M-1
    int p = idx >> 2, q = idx & 3;
    float al = alpha[0];
    float4 xr = x[(size_t)p*8 + q];
    float4 xi = x[(size_t)p*8 + 4 + q];
    float2 g[4];
    #pragma unroll
    for (int j=0;j<4;++j) g[j] = G[(size_t)(4*q+j)*NN + p];
    out[(size_t)p*8 + q]     = make_float4(xr.x - al*g[0].x, xr.y - al*g[1].x,
                                           xr.z - al*g[2].x, xr.w - al*g[3].x);
    out[(size_t)p*8 + 4 + q] = make_float4(xi.x - al*g[0].y, xi.y - al*g[1].y,
                                           xi.z - al*g[2].y, xi.w - al*g[3].y);
}

extern "C" void kernel_launch(void* const* d_in, const int* in_sizes, int n_in,
                              void* d_out, int out_size, void* d_ws, size_t ws_size,
                              hipStream_t stream)
{
    const float* x     = (const float*)d_in[0];
    const float* meas  = (const float*)d_in[1];
    const float* nail  = (const float*)d_in[2];
    const float* alpha = (const float*)d_in[3];

    if (ws_size < (size_t)21*NN*sizeof(float2)) return;

    float2* W   = (float2*)d_ws;
    float2* T   = W;                       // 16 planes; grads overwrite in place
    float2* U0  = W + (size_t)16*NN;
    float2* TAB = W + (size_t)17*NN;
    float2* TBB = W + (size_t)18*NN;
    float2* TAU = W + (size_t)19*NN;
    float2* TBU = W + (size_t)20*NN;

    const double ZP = 3.25;        // PROPKERN phase scale (dz*kz / wl units)
    const double ZF = -24.375;     // PROPKERN_FOCUS phase scale

    k_T <<<8192, 256, 0, stream>>>((const float4*)x, T);

    auto P2f = [&](double zs, float sg){
        k_pass2<<<512, 256, 0, stream>>>(TAB, TBB, nullptr, nullptr, zs, sg);
    };

    // ---------- forward + backprop mega-chain ----------
    // Pupil passes removed: KF contains the pupil mask (PC^2 = PC) and the
    // JN junction (row IFFT then row FFT) is the identity, so
    // prop(KF) ; prop(PUPIL) == prop(KF) and prop(conj PUPIL) ; prop(conj KF)
    // == prop(conj KF) exactly.
    k_head<<<512, 256, 0, stream>>>(TAB, T, nail);
    P2f(ZP, 1.0f);
    for (int z = 1; z <= 14; ++z){
        k_junc<<<512, 256, 0, stream>>>(TBB, TAB, T + (size_t)z*NN, nullptr, nullptr, JT);
        P2f(ZP, 1.0f);
    }
    k_junc<<<512, 256, 0, stream>>>(TBB, TAB, T + (size_t)15*NN, U0, nullptr, JT_WP);
    P2f(ZF, 1.0f);
    k_junc<<<512, 256, 0, stream>>>(TBB, TAB, nullptr, nullptr, meas, JRESID);
    P2f(ZF, -1.0f);

    // ---------- reverse loop: paired B/U per tile ----------
    for (int zz = 15; zz >= 1; --zz){
        k_rev<<<512, 256, 0, stream>>>(zz == 15 ? U0 : TBU, TAU, TBB, TAB,
                                       T + (size_t)zz*NN, zz == 15 ? 1 : 0);
        k_pass2<<<1024, 256, 0, stream>>>(TAB, TBB, TAU, TBU, ZP, -1.0f);
    }
    k_tail<<<512, 256, 0, stream>>>(TBU, TBB, T);

    // ---------- merge: out = x - alpha*g, straight into d_out ----------
    k_merge<<<16384, 256, 0, stream>>>((const float4*)x, T, alpha, (float4*)d_out);
}

// Round 4
// 1403.361 us; speedup vs baseline: 6.0838x; 1.0129x over previous
//
#include <hip/hip_runtime.h>
#include <math.h>

// Multislice gradient step. R4: 1024-pt complex fp32 FFT rewritten radix-4
// (4^5), 4 elems/thread, 256 lanes/row, 512-thread blocks (2 rows).
// 2x occupancy vs the radix-8/128-lane design (16 waves/CU vs 8). All
// exchanges are per-thread in-place quads -> single LDS buffer; only the
// S1<->S2 exchange crosses waves, so barriers drop to 4/kernel (pass2).
// Internal spectral order is base-4 digit-reversed; the inline Fresnel mult
// uses a digit-reverse map. Pupil section stays algebraically collapsed
// (R3). k_T / k_merge coalesced (R2).

#define NN (1024*1024)
#define KAPPA 40.840704496667314f
#define TWO_PI_F 6.2831853071795865f
#define DFX_D 0.0030048076923076925
#define RRCUT 187177
#define F(i) ((i) + ((i)>>4))
#define NTW 768

#define JT 0
#define JT_WP 1
#define JRESID 3

__device__ __forceinline__ float2 cmulf(float2 a, float2 b){
    return make_float2(a.x*b.x - a.y*b.y, a.x*b.y + a.y*b.x);
}
__device__ __forceinline__ float2 cmulcj(float2 a, float2 b){ // a * conj(b)
    return make_float2(a.x*b.x + a.y*b.y, a.y*b.x - a.x*b.y);
}
__device__ __forceinline__ float2 f2add(float2 a, float2 b){ return make_float2(a.x+b.x, a.y+b.y); }
__device__ __forceinline__ float2 f2sub(float2 a, float2 b){ return make_float2(a.x-b.x, a.y-b.y); }

// tw[k] = exp(-2*pi*i*k/1024), k < 768 (max radix-4 exponent 3*255 = 765)
__device__ __forceinline__ void fill_tw768(float2* tw, int tid){
    for (int k = tid; k < NTW; k += 512){
        float s, c; sincosf(-(float)k * (TWO_PI_F/1024.0f), &s, &c);
        tw[k] = make_float2(c, s);
    }
}

// ---------- radix-4 butterflies ----------
// DIF: X_q = sum_m x_m (-j)^{qm}, outputs scaled by W^{e q}
__device__ __forceinline__ void r4dif_tw(float2 r[4], const float2* tw, int e){
    float2 A = f2add(r[0], r[2]), B = f2sub(r[0], r[2]);
    float2 C = f2add(r[1], r[3]), D = f2sub(r[1], r[3]);
    float2 jD = make_float2(-D.y, D.x);
    r[0] = f2add(A, C);
    r[1] = cmulf(f2sub(B, jD), tw[e]);
    r[2] = cmulf(f2sub(A, C), tw[2*e]);
    r[3] = cmulf(f2add(B, jD), tw[3*e]);
}
__device__ __forceinline__ void r4dif_nt(float2 r[4]){
    float2 A = f2add(r[0], r[2]), B = f2sub(r[0], r[2]);
    float2 C = f2add(r[1], r[3]), D = f2sub(r[1], r[3]);
    float2 jD = make_float2(-D.y, D.x);
    r[0] = f2add(A, C);
    r[1] = f2sub(B, jD);
    r[2] = f2sub(A, C);
    r[3] = f2add(B, jD);
}
// DIT: untwiddle by conj(W^{e q}), then x_m = sum_q t_q (+j)^{qm}
__device__ __forceinline__ void r4dit_tw(float2 r[4], const float2* tw, int e){
    float2 t1 = cmulcj(r[1], tw[e]);
    float2 t2 = cmulcj(r[2], tw[2*e]);
    float2 t3 = cmulcj(r[3], tw[3*e]);
    float2 E = f2add(r[0], t2), Fv = f2sub(r[0], t2);
    float2 G = f2add(t1, t3),  H  = f2sub(t1, t3);
    float2 jH = make_float2(-H.y, H.x);
    r[0] = f2add(E, G);
    r[1] = f2add(Fv, jH);
    r[2] = f2sub(E, G);
    r[3] = f2sub(Fv, jH);
}
__device__ __forceinline__ void r4dit_nt(float2 r[4]){
    float2 E = f2add(r[0], r[2]), Fv = f2sub(r[0], r[2]);
    float2 G = f2add(r[1], r[3]), H  = f2sub(r[1], r[3]);
    float2 jH = make_float2(-H.y, H.x);
    r[0] = f2add(E, G);
    r[1] = f2add(Fv, jH);
    r[2] = f2sub(E, G);
    r[3] = f2sub(Fv, jH);
}

// ---------- full 1024-pt drivers (one row = 256 lanes x 4 elems) ----------
// dif4: entry r[m] = x[lane + 256m] (natural); exit r[q] = X at slot 4*lane+q
// (digit-reversed). One inter-wave barrier (S1->S2); S2..S5 exchanges are
// intra-wave in-place quads (per-wave lgkmcnt ordering, no barrier).
__device__ __forceinline__ void dif4(float2* L, const float2* tw, int ro, int lane,
                                     float2 r[4]){
    r4dif_tw(r, tw, lane);
    #pragma unroll
    for (int q=0;q<4;++q) L[F(ro + lane + 256*q)] = r[q];
    __syncthreads();
    const int b = lane>>6, m = lane&63, base2 = ro + 256*b + m;
    #pragma unroll
    for (int q=0;q<4;++q) r[q] = L[F(base2 + 64*q)];
    r4dif_tw(r, tw, 4*m);
    #pragma unroll
    for (int q=0;q<4;++q) L[F(base2 + 64*q)] = r[q];
    const int g = lane>>4, m3 = lane&15, base3 = ro + 64*g + m3;
    #pragma unroll
    for (int q=0;q<4;++q) r[q] = L[F(base3 + 16*q)];
    r4dif_tw(r, tw, 16*m3);
    #pragma unroll
    for (int q=0;q<4;++q) L[F(base3 + 16*q)] = r[q];
    const int h = lane>>2, m4 = lane&3, base4 = ro + 16*h + m4;
    #pragma unroll
    for (int q=0;q<4;++q) r[q] = L[F(base4 + 4*q)];
    r4dif_tw(r, tw, 64*m4);
    #pragma unroll
    for (int q=0;q<4;++q) L[F(base4 + 4*q)] = r[q];
    const int base5 = F(ro + 4*lane);      // 4*lane%16 in {0,4,8,12}: contiguous
    #pragma unroll
    for (int q=0;q<4;++q) r[q] = L[base5 + q];
    r4dif_nt(r);
}
// dit4: entry r[q] = Y at slot 4*lane+q (digit-reversed); exit r[m] =
// x[lane + 256m] (natural). One inter-wave barrier (S2'->S1').
__device__ __forceinline__ void dit4(float2* L, const float2* tw, int ro, int lane,
                                     float2 r[4]){
    r4dit_nt(r);
    const int base5 = F(ro + 4*lane);
    #pragma unroll
    for (int q=0;q<4;++q) L[base5 + q] = r[q];
    const int h = lane>>2, m4 = lane&3, base4 = ro + 16*h + m4;
    #pragma unroll
    for (int q=0;q<4;++q) r[q] = L[F(base4 + 4*q)];
    r4dit_tw(r, tw, 64*m4);
    #pragma unroll
    for (int q=0;q<4;++q) L[F(base4 + 4*q)] = r[q];
    const int g = lane>>4, m3 = lane&15, base3 = ro + 64*g + m3;
    #pragma unroll
    for (int q=0;q<4;++q) r[q] = L[F(base3 + 16*q)];
    r4dit_tw(r, tw, 16*m3);
    #pragma unroll
    for (int q=0;q<4;++q) L[F(base3 + 16*q)] = r[q];
    const int b = lane>>6, m = lane&63, base2 = ro + 256*b + m;
    #pragma unroll
    for (int q=0;q<4;++q) r[q] = L[F(base2 + 64*q)];
    r4dit_tw(r, tw, 4*m);
    #pragma unroll
    for (int q=0;q<4;++q) L[F(base2 + 64*q)] = r[q];
    __syncthreads();
    #pragma unroll
    for (int q=0;q<4;++q) r[q] = L[F(ro + lane + 256*q)];
    r4dit_tw(r, tw, lane);
}

// store digit-rev regs to slots 4*lane+q (per-thread slots: no barrier needed)
__device__ __forceinline__ void st_slot(float2* L, int ro, int lane, const float2 r[4]){
    const int base = F(ro + 4*lane);
    #pragma unroll
    for (int q=0;q<4;++q) L[base + q] = r[q];
}
// store natural regs to slots lane+256m
__device__ __forceinline__ void st_nat(float2* L, int ro, int lane, const float2 r[4]){
    #pragma unroll
    for (int m=0;m<4;++m) L[F(ro + lane + 256*m)] = r[m];
}
// consecutive-slot global load (2 x float4 per thread)
__device__ __forceinline__ void load4slot(const float2* src, int lane, float2 r[4]){
    const float4* s4 = (const float4*)src + lane*2;
    float4 v0 = s4[0], v1 = s4[1];
    r[0] = make_float2(v0.x, v0.y); r[1] = make_float2(v0.z, v0.w);
    r[2] = make_float2(v1.x, v1.y); r[3] = make_float2(v1.z, v1.w);
}
// transposed write: dst[slot][r0..r0+1] as float4, both rows of the block
__device__ __forceinline__ void twr(const float2* L, int tid, float2* dst,
                                    int r0, float s){
    #pragma unroll
    for (int k=0;k<2;++k){
        int c = tid + (k<<9);
        float2 a0 = L[F(c)], a1 = L[F(1024+c)];
        ((float4*)(dst + ((size_t)c<<10) + r0))[0] =
            make_float4(a0.x*s, a0.y*s, a1.x*s, a1.y*s);
    }
}

// ---------- chain head: u = planewave*T0, row DIF, transposed write ----------
__global__ void __launch_bounds__(512,4) k_head(float2* __restrict__ dst,
                                                const float2* __restrict__ T0,
                                                const float* __restrict__ nail){
    __shared__ float2 A[2176], tw[NTW];
    const int tid = threadIdx.x;
    fill_tw768(tw, tid);
    const int row = tid>>8, lane = tid&255, ro = row<<10;
    const int r0 = blockIdx.x*2;
    const size_t gbase = ((size_t)(r0+row))<<10;
    float dfx = (float)DFX_D;
    float t0 = rintf(nail[0]*2.0f/dfx)*dfx;
    float t1 = rintf(nail[1]*2.0f/dfx)*dfx;
    float yv = (float)((r0+row) - 512) * 0.325f;
    float2 r[4];
    #pragma unroll
    for (int m=0;m<4;++m){
        int col = lane + 256*m;
        float2 tv = T0[gbase + col];
        float xv = (float)(col - 512) * 0.325f;
        float s0, c0; sincosf(TWO_PI_F*(t0*xv + t1*yv), &s0, &c0);
        r[m] = cmulf(make_float2(c0,s0), tv);
    }
    __syncthreads();                       // tw ready
    dif4(A, tw, ro, lane, r);
    st_slot(A, ro, lane, r);
    __syncthreads();
    twr(A, tid, dst, r0, 1.0f);
}

// ---------- pass2: col DIF + inline Fresnel mult (digit-rev) + col DIT ------
__global__ void __launch_bounds__(512,4) k_pass2(
    const float2* __restrict__ srcA, float2* __restrict__ dstA,
    const float2* __restrict__ srcB, float2* __restrict__ dstB,
    double zscale, float sg)
{
    __shared__ float2 A[2176], tw[NTW];
    const int tid = threadIdx.x;
    fill_tw768(tw, tid);
    const int row = tid>>8, lane = tid&255, ro = row<<10;
    int bid = blockIdx.x;
    const float2* src = srcA; float2* dst = dstA;
    if (srcB != nullptr && bid >= 512){ src = srcB; dst = dstB; bid -= 512; }
    const int r0 = bid*2;
    const int jrow = r0 + row;
    const float2* srcR = src + (((size_t)r0)<<10) + ro;
    float2 r[4];
    #pragma unroll
    for (int m=0;m<4;++m) r[m] = srcR[lane + 256*m];
    __syncthreads();                       // tw ready
    dif4(A, tw, ro, lane, r);
    // pointwise at digit-rev slots 4*lane+q: freq = digitrev4(slot)
    {
        int jr = ((jrow&3)<<8)|(((jrow>>2)&3)<<6)|(((jrow>>4)&3)<<4)
               |(((jrow>>6)&3)<<2)|((jrow>>8)&3);
        int rb = jr - (jr >= 512 ? 1024 : 0);
        int rb2 = rb*rb;
        int lr = ((lane&3)<<6)|(((lane>>2)&3)<<4)|(((lane>>4)&3)<<2)|((lane>>6)&3);
        #pragma unroll
        for (int q=0;q<4;++q){
            int fa = (q<<8) | lr;
            int ra = fa - (fa >= 512 ? 1024 : 0);
            int rr = ra*ra + rb2;
            if (rr <= RRCUT){
                double urr = (double)rr * (DFX_D*DFX_D);
                double kz = sqrt(4.0 - urr);
                double t = zscale * kz;
                float fp = (float)(t - floor(t));
                float s, c; sincosf(TWO_PI_F*fp, &s, &c);
                r[q] = cmulf(r[q], make_float2(c, sg*s));
            } else {
                r[q] = make_float2(0.f, 0.f);
            }
        }
    }
    dit4(A, tw, ro, lane, r);
    st_nat(A, ro, lane, r);
    __syncthreads();
    twr(A, tid, dst, r0, 1.0f/1024.0f);
}

// ---------- fused junction: row DIT + pointwise + row DIF ----------
__global__ void __launch_bounds__(512,4) k_junc(
    const float2* __restrict__ src, float2* __restrict__ dst,
    const float2* __restrict__ Tz, float2* __restrict__ wp,
    const float* __restrict__ meas, int mode)
{
    __shared__ float2 A[2176], tw[NTW];
    const int tid = threadIdx.x;
    fill_tw768(tw, tid);
    const int row = tid>>8, lane = tid&255, ro = row<<10;
    const int r0 = blockIdx.x*2;
    const size_t gbase = ((size_t)(r0+row))<<10;
    const float S = 1.0f/1024.0f;
    float2 r[4];
    load4slot(src + (((size_t)r0)<<10) + ro, lane, r);
    float2 pre[4];
    if (mode == JT || mode == JT_WP){
        #pragma unroll
        for (int m=0;m<4;++m) pre[m] = Tz[gbase + lane + 256*m];
    } else if (mode == JRESID){
        #pragma unroll
        for (int m=0;m<4;++m) pre[m].x = meas[gbase + lane + 256*m];
    }
    __syncthreads();                       // tw ready
    dit4(A, tw, ro, lane, r);
    #pragma unroll
    for (int m=0;m<4;++m){
        size_t g = gbase + lane + 256*m;
        float2 v = make_float2(S*r[m].x, S*r[m].y);
        if (mode == JT || mode == JT_WP){
            v = cmulf(v, pre[m]);
            if (mode == JT_WP) wp[g] = v;
        } else if (mode == JRESID){
            float mm = pre[m].x;
            float aamp = fmaxf(sqrtf(v.x*v.x + v.y*v.y), 1e-30f);
            float f = 1.0f - sqrtf(mm)/aamp;
            v.x *= f; v.y *= f;
        }
        r[m] = v;
    }
    dif4(A, tw, ro, lane, r);
    st_slot(A, ro, lane, r);
    __syncthreads();
    twr(A, tid, dst, r0, 1.0f);
}

// ---------- reverse junction: both chains per tile; grad -> T plane ----------
__global__ void __launch_bounds__(512,4) k_rev(
    const float2* __restrict__ srcU, float2* __restrict__ dstU,
    const float2* __restrict__ srcB, float2* __restrict__ dstB,
    float2* __restrict__ Tz, int headU)
{
    __shared__ float2 A[2176], Bb[2176], tw[NTW];
    const int tid = threadIdx.x;
    fill_tw768(tw, tid);
    const int row = tid>>8, lane = tid&255, ro = row<<10;
    const int r0 = blockIdx.x*2;
    const size_t gbase = ((size_t)(r0+row))<<10;
    const float S = 1.0f/1024.0f;
    float2 u[4], Tg[4], bb[4], r[4];
    // issue all global loads up front (one latency window)
    if (!headU){
        load4slot(srcU + (((size_t)r0)<<10) + ro, lane, u);
    } else {
        const float2* sR = srcU + (((size_t)r0)<<10) + ro;
        #pragma unroll
        for (int m=0;m<4;++m) u[m] = sR[lane + 256*m];
    }
    #pragma unroll
    for (int m=0;m<4;++m) Tg[m] = Tz[gbase + lane + 256*m];
    load4slot(srcB + (((size_t)r0)<<10) + ro, lane, bb);
    __syncthreads();                       // tw ready
    // ---- U chain ----
    if (!headU){
        dit4(A, tw, ro, lane, u);
        #pragma unroll
        for (int m=0;m<4;++m){ u[m].x *= S; u[m].y *= S; }
    }
    #pragma unroll
    for (int m=0;m<4;++m){
        if (headU) r[m] = u[m];
        else {
            float inv = 1.0f/(Tg[m].x*Tg[m].x + Tg[m].y*Tg[m].y);
            float2 wc = cmulcj(u[m], Tg[m]);
            r[m] = make_float2(wc.x*inv, wc.y*inv);
        }
    }
    dif4(A, tw, ro, lane, r);
    st_slot(A, ro, lane, r);
    __syncthreads();
    twr(A, tid, dstU, r0, 1.0f);
    // ---- B chain (buffer Bb: independent of A's twr reads) ----
    dit4(Bb, tw, ro, lane, bb);
    #pragma unroll
    for (int m=0;m<4;++m){
        float2 b2 = make_float2(S*bb[m].x, S*bb[m].y);
        float2 q2 = headU ? cmulcj(cmulcj(b2, u[m]), Tg[m]) : cmulcj(b2, u[m]);
        Tz[gbase + lane + 256*m] = make_float2(KAPPA*q2.y, -KAPPA*q2.x);
        r[m] = cmulcj(b2, Tg[m]);
    }
    dif4(Bb, tw, ro, lane, r);
    st_slot(Bb, ro, lane, r);
    __syncthreads();
    twr(Bb, tid, dstB, r0, 1.0f);
}

// ---------- tail: finish both chains, grad[0] -> T plane 0 ----------
__global__ void __launch_bounds__(512,4) k_tail(
    const float2* __restrict__ srcU, const float2* __restrict__ srcB,
    float2* __restrict__ G0)
{
    __shared__ float2 A[2176], Bb[2176], tw[NTW];
    const int tid = threadIdx.x;
    fill_tw768(tw, tid);
    const int row = tid>>8, lane = tid&255, ro = row<<10;
    const int r0 = blockIdx.x*2;
    const size_t gbase = ((size_t)(r0+row))<<10;
    const float S = 1.0f/1024.0f;
    float2 u[4], r[4];
    load4slot(srcU + (((size_t)r0)<<10) + ro, lane, u);
    load4slot(srcB + (((size_t)r0)<<10) + ro, lane, r);
    __syncthreads();                       // tw ready
    dit4(A,  tw, ro, lane, u);
    dit4(Bb, tw, ro, lane, r);
    #pragma unroll
    for (int m=0;m<4;++m){
        float2 b2 = make_float2(S*r[m].x, S*r[m].y);
        float2 w2 = make_float2(S*u[m].x, S*u[m].y);
        float2 q2 = cmulcj(b2, w2);
        G0[gbase + lane + 256*m] = make_float2(KAPPA*q2.y, -KAPPA*q2.x);
    }
}

// k_T: one thread per (pixel-pair, z-quad); 64 B in / 64 B out, float4 stores.
__global__ void __launch_bounds__(256) k_T(const float4* __restrict__ x,
                                           float2* __restrict__ T){
    int idx = blockIdx.x*256 + threadIdx.x;    // 0 .. 2M-1
    int pp = idx >> 2;                         // pixel pair
    int q  = idx & 3;                          // z-quad
    int p0 = pp*2;
    float4 vr0 = x[(size_t)p0*8 + q];
    float4 vi0 = x[(size_t)p0*8 + 4 + q];
    float4 vr1 = x[(size_t)(p0+1)*8 + q];
    float4 vi1 = x[(size_t)(p0+1)*8 + 4 + q];
    const float* fr0 = (const float*)&vr0;
    const float* fi0 = (const float*)&vi0;
    const float* fr1 = (const float*)&vr1;
    const float* fi1 = (const float*)&vi1;
    #pragma unroll
    for (int j=0;j<4;++j){
        int z = 4*q + j;
        float a0 = __expf(-KAPPA*fi0[j]);
        float s0, c0; __sincosf(KAPPA*fr0[j], &s0, &c0);
        float a1 = __expf(-KAPPA*fi1[j]);
        float s1, c1; __sincosf(KAPPA*fr1[j], &s1, &c1);
        ((float4*)(T + (size_t)z*NN + p0))[0] = make_float4(a0*c0, a0*s0, a1*c1, a1*s1);
    }
}

// k_merge: one thread per (pixel, z-quad) handling real+imag float4s.
__global__ void __launch_bounds__(256) k_merge(const float4* __restrict__ x,
                                               const float2* __restrict__ G,
                                               const float* __restrict__ alpha,
                                               float4* __restrict__ out){
    int idx = blockIdx.x*256 + threadIdx.x;    // 0 .. 4M-1
    int p = idx >> 2, q = idx & 3;
    float al = alpha[0];
    float4 xr = x[(size_t)p*8 + q];
    float4 xi = x[(size_t)p*8 + 4 + q];
    float2 g[4];
    #pragma unroll
    for (int j=0;j<4;++j) g[j] = G[(size_t)(4*q+j)*NN + p];
    out[(size_t)p*8 + q]     = make_float4(xr.x - al*g[0].x, xr.y - al*g[1].x,
                                           xr.z - al*g[2].x, xr.w - al*g[3].x);
    out[(size_t)p*8 + 4 + q] = make_float4(xi.x - al*g[0].y, xi.y - al*g[1].y,
                                           xi.z - al*g[2].y, xi.w - al*g[3].y);
}

extern "C" void kernel_launch(void* const* d_in, const int* in_sizes, int n_in,
                              void* d_out, int out_size, void* d_ws, size_t ws_size,
                              hipStream_t stream)
{
    const float* x     = (const float*)d_in[0];
    const float* meas  = (const float*)d_in[1];
    const float* nail  = (const float*)d_in[2];
    const float* alpha = (const float*)d_in[3];

    if (ws_size < (size_t)21*NN*sizeof(float2)) return;

    float2* W   = (float2*)d_ws;
    float2* T   = W;                       // 16 planes; grads overwrite in place
    float2* U0  = W + (size_t)16*NN;
    float2* TAB = W + (size_t)17*NN;
    float2* TBB = W + (size_t)18*NN;
    float2* TAU = W + (size_t)19*NN;
    float2* TBU = W + (size_t)20*NN;

    const double ZP = 3.25;        // PROPKERN phase scale
    const double ZF = -24.375;     // PROPKERN_FOCUS phase scale

    k_T <<<8192, 256, 0, stream>>>((const float4*)x, T);

    auto P2f = [&](double zs, float sg){
        k_pass2<<<512, 512, 0, stream>>>(TAB, TBB, nullptr, nullptr, zs, sg);
    };

    // ---------- forward + backprop mega-chain (pupil passes collapsed) -----
    k_head<<<512, 512, 0, stream>>>(TAB, T, nail);
    P2f(ZP, 1.0f);
    for (int z = 1; z <= 14; ++z){
        k_junc<<<512, 512, 0, stream>>>(TBB, TAB, T + (size_t)z*NN, nullptr, nullptr, JT);
        P2f(ZP, 1.0f);
    }
    k_junc<<<512, 512, 0, stream>>>(TBB, TAB, T + (size_t)15*NN, U0, nullptr, JT_WP);
    P2f(ZF, 1.0f);
    k_junc<<<512, 512, 0, stream>>>(TBB, TAB, nullptr, nullptr, meas, JRESID);
    P2f(ZF, -1.0f);

    // ---------- reverse loop: paired B/U per tile ----------
    for (int zz = 15; zz >= 1; --zz){
        k_rev<<<512, 512, 0, stream>>>(zz == 15 ? U0 : TBU, TAU, TBB, TAB,
                                       T + (size_t)zz*NN, zz == 15 ? 1 : 0);
        k_pass2<<<1024, 512, 0, stream>>>(TAB, TBB, TAU, TBU, ZP, -1.0f);
    }
    k_tail<<<512, 512, 0, stream>>>(TBU, TBB, T);

    // ---------- merge: out = x - alpha*g, straight into d_out ----------
    k_merge<<<16384, 256, 0, stream>>>((const float4*)x, T, alpha, (float4*)d_out);
}